// Round 4
// baseline (1780.676 us; speedup 1.0000x reference)
//
#include <hip/hip_runtime.h>
#include <math.h>

typedef float floatx4 __attribute__((ext_vector_type(4)));
typedef __bf16 bf16x8 __attribute__((ext_vector_type(8)));
typedef unsigned short ushortx8 __attribute__((ext_vector_type(8)));
typedef unsigned short ushortx4 __attribute__((ext_vector_type(4)));
typedef unsigned short ushortx2 __attribute__((ext_vector_type(2)));

typedef unsigned int __attribute__((address_space(1))) as1_uint;
typedef unsigned int __attribute__((address_space(3))) as3_uint;

#define DEV static __device__ __forceinline__

DEV unsigned short f32_bf16(float f) {
  unsigned u = __float_as_uint(f);
  u += 0x7FFFu + ((u >> 16) & 1u);
  return (unsigned short)(u >> 16);
}
DEV float bf16_f32(unsigned short h) { return __uint_as_float(((unsigned)h) << 16); }
DEV float gelu_f(float x) {
  // 0.5x(1+tanh(t)) == x * sigmoid(2t); error vs tanhf ~1e-7 rel, << bf16 ulp
  float t2 = 1.5957691216057308f * (x + 0.044715f * x * x * x);
  return x * __builtin_amdgcn_rcpf(1.0f + __expf(-t2));
}
DEV void gload16(const void* g, void* l) {
  __builtin_amdgcn_global_load_lds((const as1_uint*)g, (as3_uint*)l, 16, 0, 0);
}
DEV floatx4 mfma16(ushortx8 a, ushortx8 b, floatx4 c) {
  return __builtin_amdgcn_mfma_f32_16x16x32_bf16(
      __builtin_bit_cast(bf16x8, a), __builtin_bit_cast(bf16x8, b), c, 0, 0, 0);
}

// ---------------- small kernels ----------------

__global__ void zero_f(float* p, int n) {
  int i = threadIdx.x;
  if (i < n) p[i] = 0.f;
}

__global__ void cvt_f32_bf16(const float* __restrict__ in, unsigned short* __restrict__ out,
                             long n4) {
  long i = (long)blockIdx.x * blockDim.x + threadIdx.x;
  if (i >= n4) return;
  float4 v = ((const float4*)in)[i];
  ushortx4 o;
  o.x = f32_bf16(v.x); o.y = f32_bf16(v.y); o.z = f32_bf16(v.z); o.w = f32_bf16(v.w);
  ((ushortx4*)out)[i] = o;
}

// out[n*cw + k] = in[n*8192 + cbase + k], n<2048, k<cw ; cwlog4 = log2(cw/4)
__global__ void cvt_cols(const float* __restrict__ in, unsigned short* __restrict__ out,
                         int cbase, int cwlog4, long n4) {
  long i = (long)blockIdx.x * blockDim.x + threadIdx.x;
  if (i >= n4) return;
  int n = (int)(i >> cwlog4);
  int k4 = (int)(i & ((1 << cwlog4) - 1)) << 2;
  float4 v = *(const float4*)&in[(size_t)n * 8192 + cbase + k4];
  ushortx4 o;
  o.x = f32_bf16(v.x); o.y = f32_bf16(v.y); o.z = f32_bf16(v.z); o.w = f32_bf16(v.w);
  *(ushortx4*)&out[((size_t)n << (cwlog4 + 2)) + k4] = o;
}

// one wave per (bh,d) row of 128; sums 4 K-split partials (stride 1Mi floats),
// scale by 1/sqrt(S), softmax, bf16 out
__global__ __launch_bounds__(256) void softmax_k(const float* __restrict__ sc,
                                                 unsigned short* __restrict__ probs) {
  int r = blockIdx.x * 4 + (threadIdx.x >> 6);
  int lane = threadIdx.x & 63;
  size_t base = (size_t)(r >> 7) * 16384 + (size_t)(r & 127) * 128 + lane * 2;
  float2 p0 = *(const float2*)&sc[base];
  float2 p1 = *(const float2*)&sc[base + 1048576];
  float2 p2 = *(const float2*)&sc[base + 2097152];
  float2 p3 = *(const float2*)&sc[base + 3145728];
  const float scale = 0.022097086912079608f;  // 1/sqrt(2048)
  float vx = (p0.x + p1.x + p2.x + p3.x) * scale;
  float vy = (p0.y + p1.y + p2.y + p3.y) * scale;
  float m = fmaxf(vx, vy);
#pragma unroll
  for (int off = 32; off; off >>= 1) m = fmaxf(m, __shfl_xor(m, off));
  float ex = expf(vx - m), ey = expf(vy - m);
  float s = ex + ey;
#pragma unroll
  for (int off = 32; off; off >>= 1) s += __shfl_xor(s, off);
  float inv = 1.f / s;
  ushortx2 o;
  o.x = f32_bf16(ex * inv);
  o.y = f32_bf16(ey * inv);
  *(ushortx2*)&probs[base] = o;
}

// global layernorm apply: out = (r - mean)*rstd*w[col] + b[col]
__global__ void ln_apply(const float* __restrict__ r, const float* __restrict__ stats,
                         const float* __restrict__ w, const float* __restrict__ bia,
                         float* __restrict__ outF, unsigned short* __restrict__ outB, long n4) {
  long i = (long)blockIdx.x * blockDim.x + threadIdx.x;
  if (i >= n4) return;
  const double total = 16777216.0;
  double mean = (double)stats[0] / total;
  double var = ((double)stats[1] - total * mean * mean) / (total - 1.0);
  float rstd = (float)(1.0 / sqrt(var + 1e-12));
  float fm = (float)mean;
  int col = (int)((i * 4) & 2047);
  float4 v = ((const float4*)r)[i];
  float4 wv = *(const float4*)&w[col];
  float4 bv = *(const float4*)&bia[col];
  float4 o;
  o.x = (v.x - fm) * rstd * wv.x + bv.x;
  o.y = (v.y - fm) * rstd * wv.y + bv.y;
  o.z = (v.z - fm) * rstd * wv.z + bv.z;
  o.w = (v.w - fm) * rstd * wv.w + bv.w;
  if (outF) ((float4*)outF)[i] = o;
  if (outB) {
    ushortx4 ob;
    ob.x = f32_bf16(o.x); ob.y = f32_bf16(o.y); ob.z = f32_bf16(o.z); ob.w = f32_bf16(o.w);
    ((ushortx4*)outB)[i] = ob;
  }
}

// ---------------- 128-tile GEMM (kept for scores / PV, z-sliced) ----------------
__global__ __launch_bounds__(256) void gemm_bt(
    const unsigned short* __restrict__ A, int lda, long sAo, long sAi,
    const unsigned short* __restrict__ B, int ldb, long sBo, long sBi,
    int K, int innerCnt,
    const float* __restrict__ bias, const float* __restrict__ residF,
    const unsigned short* __restrict__ residB, int accum,
    float* __restrict__ outF, unsigned short* __restrict__ outB,
    unsigned short* __restrict__ outQT,
    int ldc, long sCo, long sCi, int doGelu, float* __restrict__ stats) {
  __shared__ unsigned short As[128 * 64];
  __shared__ unsigned short Bs[128 * 64];
  const int tid = threadIdx.x;
  const int wave = tid >> 6;
  const int lane = tid & 63;
  const int z = blockIdx.z;
  const int zo = z / innerCnt, zi = z % innerCnt;
  const unsigned short* Ab = A + zo * sAo + zi * sAi;
  const unsigned short* Bb = B + zo * sBo + zi * sBi;
  const long coff = zo * sCo + zi * sCi;
  const int m0 = blockIdx.y * 128;
  const int n0 = blockIdx.x * 128;

  const int quad = lane >> 4;
  const int l16 = lane & 15;
  const int wm = (wave & 1) * 64;
  const int wn = (wave >> 1) * 64;
  const int srow = lane >> 3;
  const int kofs8 = (((lane & 7) ^ srow) & 7) * 8;

  floatx4 acc[4][4];
#pragma unroll
  for (int i = 0; i < 4; i++)
#pragma unroll
    for (int j = 0; j < 4; j++) acc[i][j] = (floatx4){0.f, 0.f, 0.f, 0.f};

  const int nK = K >> 6;
  for (int kt = 0; kt < nK; ++kt) {
    const int k0 = kt << 6;
    __syncthreads();
#pragma unroll
    for (int i = 0; i < 4; ++i) {
      const int rb = wave * 32 + i * 8;
      gload16(Ab + (size_t)(m0 + rb + srow) * lda + k0 + kofs8, &As[rb * 64]);
      gload16(Bb + (size_t)(n0 + rb + srow) * ldb + k0 + kofs8, &Bs[rb * 64]);
    }
    __syncthreads();
#pragma unroll
    for (int kk = 0; kk < 2; ++kk) {
      ushortx8 af[4], bf[4];
      const int swz = (l16 & 7);
#pragma unroll
      for (int i = 0; i < 4; i++)
        af[i] = *(const ushortx8*)&As[(wm + i * 16 + l16) * 64 +
                                      (((kk * 4 + quad) ^ swz) * 8)];
#pragma unroll
      for (int j = 0; j < 4; j++)
        bf[j] = *(const ushortx8*)&Bs[(wn + j * 16 + l16) * 64 +
                                      (((kk * 4 + quad) ^ swz) * 8)];
#pragma unroll
      for (int i = 0; i < 4; i++)
#pragma unroll
        for (int j = 0; j < 4; j++) acc[i][j] = mfma16(af[i], bf[j], acc[i][j]);
    }
  }

  float s1 = 0.f, s2 = 0.f;
#pragma unroll
  for (int i = 0; i < 4; i++) {
#pragma unroll
    for (int j = 0; j < 4; j++) {
      const int col = n0 + wn + j * 16 + l16;
      const float bv = bias ? bias[col] : 0.f;
#pragma unroll
      for (int r = 0; r < 4; r++) {
        const int row = m0 + wm + i * 16 + quad * 4 + r;
        float v = acc[i][j][r] + bv;
        if (doGelu) v = gelu_f(v);
        if (outQT) {
          const int b = row >> 11, s = row & 2047;
          if (col < 4096) {
            unsigned short* tb = outQT + ((col & 2048) ? 16777216u : 0u);
            const int cc = col & 2047;
            tb[((size_t)((b << 4) + (cc >> 7)) * 128 + (cc & 127)) * 2048 + s] = f32_bf16(v);
          } else {
            outB[(size_t)row * 2048 + (col - 4096)] = f32_bf16(v);
          }
          continue;
        }
        const size_t cidx = (size_t)coff + (size_t)row * ldc + col;
        if (residF) v += residF[cidx];
        if (residB) v += bf16_f32(residB[cidx]);
        if (accum) v += outF[cidx];
        if (outF) outF[cidx] = v;
        else outB[cidx] = f32_bf16(v);
        if (stats) { s1 += v; s2 += v * v; }
      }
    }
  }
  if (stats) {
#pragma unroll
    for (int off = 32; off; off >>= 1) {
      s1 += __shfl_down(s1, off);
      s2 += __shfl_down(s2, off);
    }
    if (lane == 0) {
      atomicAdd(&stats[0], s1);
      atomicAdd(&stats[1], s2);
    }
  }
}

// ---------------- 256x256 single-barrier-per-K-tile GEMM ----------------
// Round-4: rounds 1-3 all measured ~2184 cy/phase regardless of wait
// discipline -> the 8-barrier-pair lockstep itself (plus possibly coarse
// LDS-DMA alias waits before ds_reads) was the invariant cost. New K-loop,
// one barrier + one (covered) vmcnt drain per 64-wide K-tile:
//   [24 ds_read_b128 of buf P] -> sched_barrier(0) ->
//   [8 global_load_lds: all of tile kt+1 -> buf P^1] ->
//   [64 MFMA (HW overlaps LDS service via in-order partial lgkm waits)] ->
//   vmcnt(0) (covered by the ~2500cy MFMA window) -> s_barrier.
// H1-immune: every ds_read batch executes at vmcnt==0 (drained at previous
// tile end), so even a conservative compiler-inserted DMA-alias wait is
// free; sched_barrier(0) keeps stage issues from hoisting above the reads.
// Race audit: reads of P are consumed by MFMA before the barrier; DMA into
// P is issued only after that barrier; DMA into P^1 retired (own vmcnt(0)
// + barrier join) before any wave reads P^1.  Requires K%128==0.
__global__ __launch_bounds__(512, 2) void gemm256(
    const unsigned short* __restrict__ A, int lda,
    const unsigned short* __restrict__ B, int ldb, int K,
    const float* __restrict__ bias, const float* __restrict__ residF,
    const unsigned short* __restrict__ residB, int accum,
    float* __restrict__ outF, unsigned short* __restrict__ outB,
    unsigned short* __restrict__ outQT, int ldc, int doGelu,
    float* __restrict__ stats) {
  __shared__ unsigned short As0[256 * 64];
  __shared__ unsigned short As1[256 * 64];
  __shared__ unsigned short Bs0[256 * 64];
  __shared__ unsigned short Bs1[256 * 64];
  const int tid = threadIdx.x;
  const int wave = tid >> 6;     // 0..7
  const int lane = tid & 63;
  const int wm = wave >> 2;      // 0..1  (M)
  const int wn = wave & 3;       // 0..3  (N)
  const int quad = lane >> 4;
  const int l16 = lane & 15;
  const int swz = l16 & 7;

  // bijective XCD-chunked swizzle (m204) + rectangular intra-XCD mapping
  const int nwg = gridDim.x * gridDim.y;
  const int orig = blockIdx.y * gridDim.x + blockIdx.x;
  const int q8 = nwg >> 3, r8 = nwg & 7;
  const int xcd = orig & 7, lid = orig >> 3;
  const int wgid = (xcd < r8 ? xcd * (q8 + 1) : r8 * (q8 + 1) + (xcd - r8) * q8) + lid;
  int m0, n0;
  if ((gridDim.x & 7) == 0) {
    const int gper = (int)(gridDim.y << 3);
    m0 = ((wgid % gper) >> 3) * 256;
    n0 = (((wgid / gper) << 3) + (wgid & 7)) * 256;
  } else {
    m0 = (wgid / gridDim.x) * 256;
    n0 = (wgid % gridDim.x) * 256;
  }

  const int srow = lane >> 3;
  const int kof = (((lane & 7) ^ srow) & 7) << 3;  // pre-swizzled global k-offset
  const int nkt = K >> 6;                          // even, >= 2

  floatx4 acc[8][4];
#pragma unroll
  for (int i = 0; i < 8; i++)
#pragma unroll
    for (int j = 0; j < 4; j++) acc[i][j] = (floatx4){0.f, 0.f, 0.f, 0.f};

  // stage all of K-tile kt into (Aw,Bw): 8 gload16/thread (64KB/block)
  auto stageTile = [&](unsigned short* Aw, unsigned short* Bw, int kt) {
    const int k0 = kt << 6;
#pragma unroll
    for (int s = 0; s < 2; s++) {
      const int rb = s * 128 + wave * 16;
      gload16(B + (size_t)(n0 + rb + srow) * ldb + k0 + kof, &Bw[rb * 64]);
      gload16(B + (size_t)(n0 + rb + 8 + srow) * ldb + k0 + kof, &Bw[(rb + 8) * 64]);
    }
#pragma unroll
    for (int hi = 0; hi < 2; hi++) {
      const int rb = ((wave & 4) << 5) + ((wave & 3) << 4) + hi * 64;
      gload16(A + (size_t)(m0 + rb + srow) * lda + k0 + kof, &Aw[rb * 64]);
      gload16(A + (size_t)(m0 + rb + 8 + srow) * lda + k0 + kof, &Aw[(rb + 8) * 64]);
    }
  };

  const int aBase = (wm * 128 + l16) * 64;
  const int bBase = (wn * 64 + l16) * 64;
  const int kq0 = (quad ^ swz) << 3;
  const int kq1 = ((4 + quad) ^ swz) << 3;

  // one K-tile: reads -> fence -> stage next -> MFMA -> vmcnt(0) -> barrier
  auto tile = [&](const unsigned short* Ar, const unsigned short* Br,
                  unsigned short* Aw, unsigned short* Bw, int ktNext, bool doStage) {
    ushortx8 bfr[4][2], afr[8][2];
#pragma unroll
    for (int fj = 0; fj < 4; fj++) {
      bfr[fj][0] = *(const ushortx8*)&Br[bBase + fj * 1024 + kq0];
      bfr[fj][1] = *(const ushortx8*)&Br[bBase + fj * 1024 + kq1];
    }
#pragma unroll
    for (int m = 0; m < 8; m++) {
      afr[m][0] = *(const ushortx8*)&Ar[aBase + m * 1024 + kq0];
      afr[m][1] = *(const ushortx8*)&Ar[aBase + m * 1024 + kq1];
    }
    __builtin_amdgcn_sched_barrier(0);  // stages must not hoist above reads
    if (doStage) stageTile(Aw, Bw, ktNext);
    __builtin_amdgcn_s_setprio(1);
#pragma unroll
    for (int m = 0; m < 8; m++)
#pragma unroll
      for (int n = 0; n < 4; n++) {
        acc[m][n] = mfma16(afr[m][0], bfr[n][0], acc[m][n]);
        acc[m][n] = mfma16(afr[m][1], bfr[n][1], acc[m][n]);
      }
    __builtin_amdgcn_s_setprio(0);
    asm volatile("s_waitcnt vmcnt(0)" ::: "memory");
    __builtin_amdgcn_s_barrier();
  };

  // prologue: tile 0 -> As0/Bs0
  stageTile(As0, Bs0, 0);
  asm volatile("s_waitcnt vmcnt(0)" ::: "memory");
  __builtin_amdgcn_s_barrier();

  for (int kt = 0; kt < nkt; kt += 2) {
    tile(As0, Bs0, As1, Bs1, kt + 1, true);            // kt+1 < nkt (nkt even)
    tile(As1, Bs1, As0, Bs0, kt + 2, kt + 2 < nkt);
  }

  // ---------------- epilogue ----------------
  if (outQT) {
    if (n0 < 4096) {
      // q/k: per-wave LDS transpose bounce -> coalesced 16B stores.
      // wave-private 16KB region; layout [c 64][s 128] bf16 with 8B-slot
      // swizzle phys = slot ^ (c&6) (pair-preserving for b128 reads).
      unsigned short* trb = (wave < 4) ? As0 + wave * 8192 : Bs0 + (wave - 4) * 8192;
#pragma unroll
      for (int j = 0; j < 4; j++) {
        const int c = j * 16 + l16;
        const float bv = bias ? bias[n0 + wn * 64 + c] : 0.f;
#pragma unroll
        for (int i = 0; i < 8; i++) {
          ushortx4 o;
          o.x = f32_bf16(acc[i][j][0] + bv);
          o.y = f32_bf16(acc[i][j][1] + bv);
          o.z = f32_bf16(acc[i][j][2] + bv);
          o.w = f32_bf16(acc[i][j][3] + bv);
          *(ushortx4*)&trb[c * 128 + (((i * 4 + quad) ^ (c & 6)) << 2)] = o;
        }
      }
      const int bb = m0 >> 11;
      const int sbase = (m0 & 2047) + wm * 128;
      unsigned short* tb = outQT + ((n0 & 2048) ? 16777216u : 0u);
      const int cg = lane >> 4;   // 0..3
      const int sl = lane & 15;   // covers s in 8-elem chunks
#pragma unroll
      for (int it = 0; it < 16; it++) {
        const int c = it * 4 + cg;
        ushortx8 v = *(const ushortx8*)&trb[c * 128 + (((2 * sl) ^ (c & 6)) << 2)];
        const int cc = (n0 + wn * 64 + c) & 2047;
        unsigned short* dst = tb +
            ((size_t)((bb << 4) + (cc >> 7)) * 128 + (cc & 127)) * 2048 + sbase + sl * 8;
        *(ushortx8*)dst = v;
      }
    } else {
      // V: direct store (row-major, 32B runs)
#pragma unroll
      for (int i = 0; i < 8; i++)
#pragma unroll
        for (int j = 0; j < 4; j++) {
          const int col = n0 + wn * 64 + j * 16 + l16;
          const float bv = bias ? bias[col] : 0.f;
#pragma unroll
          for (int r = 0; r < 4; r++) {
            const int row = m0 + wm * 128 + i * 16 + quad * 4 + r;
            outB[(size_t)row * 2048 + (col - 4096)] = f32_bf16(acc[i][j][r] + bv);
          }
        }
    }
    return;
  }

  float s1 = 0.f, s2 = 0.f;
#pragma unroll
  for (int i = 0; i < 8; i++) {
#pragma unroll
    for (int j = 0; j < 4; j++) {
      const int col = n0 + wn * 64 + j * 16 + l16;
      const float bv = bias ? bias[col] : 0.f;
#pragma unroll
      for (int r = 0; r < 4; r++) {
        const int row = m0 + wm * 128 + i * 16 + quad * 4 + r;
        float v = acc[i][j][r] + bv;
        if (doGelu) v = gelu_f(v);
        const size_t cidx = (size_t)row * ldc + col;
        if (residF) v += residF[cidx];
        if (residB) v += bf16_f32(residB[cidx]);
        if (accum) v += outF[cidx];
        if (outF) outF[cidx] = v;
        else outB[cidx] = f32_bf16(v);
        if (stats) { s1 += v; s2 += v * v; }
      }
    }
  }
  if (stats) {
#pragma unroll
    for (int off = 32; off; off >>= 1) {
      s1 += __shfl_down(s1, off);
      s2 += __shfl_down(s2, off);
    }
    if (lane == 0) {
      atomicAdd(&stats[0], s1);
      atomicAdd(&stats[1], s2);
    }
  }
}

// ---------------- launch ----------------
// Workspace (region lifetimes overlapped), base 152 MiB:
//   P0 32MiB: xbf -> attnbf -> hchunk(nc=4)
//   P1 24MiB: W1bf -> {spart 4x4MiB + probs(2) @ +16Mi} -> W2bf(8) -> {fc_ch+pj_ch} (nc=4)
//   P2 96MiB: {vbf(32)+qT(32)+kT(32)} -> {r12 fp32(64) + x1bf(32)}
//   P3 (optional, ws-adaptive): FFN fc/pj/h for nc=1 (192MiB) or nc=2 (96MiB)

extern "C" void kernel_launch(void* const* d_in, const int* in_sizes, int n_in, void* d_out,
                              int out_size, void* d_ws, size_t ws_size, hipStream_t stream) {
  (void)in_sizes; (void)n_in; (void)out_size;
  const float* x    = (const float*)d_in[0];
  const float* W1w  = (const float*)d_in[1];
  const float* W1b  = (const float*)d_in[2];
  const float* W2w  = (const float*)d_in[3];
  const float* W2b  = (const float*)d_in[4];
  const float* fcw  = (const float*)d_in[5];
  const float* fcb  = (const float*)d_in[6];
  const float* pjw  = (const float*)d_in[7];
  const float* pjb  = (const float*)d_in[8];
  const float* ln1w = (const float*)d_in[9];
  const float* ln1b = (const float*)d_in[10];
  const float* ln2w = (const float*)d_in[11];
  const float* ln2b = (const float*)d_in[12];
  float* out = (float*)d_out;

  char* ws = (char*)d_ws;
  size_t off = 0;
  auto take = [&](size_t b) { size_t r = off; off = (off + b + 255) & ~(size_t)255; return r; };
  float* stats = (float*)(ws + take(256));
  size_t P0 = take(33554432);
  size_t P1 = take(25165824);
  size_t P2 = take(100663296);
  size_t P3 = off;

  unsigned short* xbf    = (unsigned short*)(ws + P0);
  unsigned short* attnbf = (unsigned short*)(ws + P0);
  unsigned short* W1bf   = (unsigned short*)(ws + P1);
  float*          spart  = (float*)(ws + P1);                      // 4 partials x 4MiB
  unsigned short* probs  = (unsigned short*)(ws + P1 + 16777216);  // 2MiB
  unsigned short* W2bf   = (unsigned short*)(ws + P1);
  unsigned short* vbf    = (unsigned short*)(ws + P2);
  unsigned short* qT     = (unsigned short*)(ws + P2 + 33554432);  // kT = qT + 16Mi elems
  float*          r12    = (float*)(ws + P2);
  unsigned short* x1bf   = (unsigned short*)(ws + P2 + 67108864);

  // ws-adaptive FFN chunking
  int nc;
  unsigned short *fc_ch, *pj_ch, *hch;
  if (ws_size >= P3 + 201326592) {  // 192 MiB extra
    nc = 1;
    fc_ch = (unsigned short*)(ws + P3);
    pj_ch = (unsigned short*)(ws + P3 + 33554432);
    hch   = (unsigned short*)(ws + P3 + 67108864);
  } else if (ws_size >= P3 + 100663296) {  // 96 MiB extra
    nc = 2;
    fc_ch = (unsigned short*)(ws + P3);
    pj_ch = (unsigned short*)(ws + P3 + 16777216);
    hch   = (unsigned short*)(ws + P3 + 33554432);
  } else {
    nc = 4;
    fc_ch = (unsigned short*)(ws + P1);
    pj_ch = (unsigned short*)(ws + P1 + 8388608);
    hch   = (unsigned short*)(ws + P0);
  }
  const int cw = 8192 / nc;
  const int cwlog4 = (nc == 1) ? 11 : (nc == 2) ? 10 : 9;
  const long cn4 = (long)cw << 9;  // cw*2048/4

  zero_f<<<1, 64, 0, stream>>>(stats, 16);
  cvt_f32_bf16<<<16384, 256, 0, stream>>>(x, xbf, 4194304);
  cvt_f32_bf16<<<12288, 256, 0, stream>>>(W1w, W1bf, 3145728);

  // QKV: [8192,2048] @ [6144,2048]^T + W1_b -> qT/kT [b,h,128,2048] + vbf [8192,2048]
  gemm256<<<dim3(24, 32, 1), 512, 0, stream>>>(xbf, 2048, W1bf, 2048, 2048, W1b, nullptr,
                                               nullptr, 0, nullptr, vbf, qT, 0, 0, nullptr);
  // scores per (b,h), K split 4-way: qT[128,512-slice] @ kT^T -> 4 fp32 partials
  gemm_bt<<<dim3(1, 1, 256), 256, 0, stream>>>(qT, 2048, 262144L, 512L, qT + 16777216, 2048,
                                               262144L, 512L, 512, 4, nullptr, nullptr, nullptr,
                                               0, spart, nullptr, nullptr, 128, 16384L, 1048576L,
                                               0, nullptr);
  softmax_k<<<2048, 256, 0, stream>>>(spart, probs);
  // PV per (b,h): P[128,128] @ V[2048,128]^T -> attn2d[b, h*128+d, s] bf16
  gemm_bt<<<dim3(16, 1, 64), 256, 0, stream>>>(probs, 128, 262144L, 16384L, vbf, 2048, 4194304L,
                                               128L, 128, 16, nullptr, nullptr, nullptr, 0,
                                               nullptr, attnbf, nullptr, 2048, 4194304L, 262144L,
                                               0, nullptr);
  cvt_f32_bf16<<<4096, 256, 0, stream>>>(W2w, W2bf, 1048576);
  // W2 + bias + residual(x fp32) -> r1 fp32, stats[0:2]
  gemm256<<<dim3(8, 32, 1), 512, 0, stream>>>(attnbf, 2048, W2bf, 2048, 2048, W2b, x, nullptr,
                                              0, r12, nullptr, nullptr, 2048, 0, stats);
  ln_apply<<<16384, 256, 0, stream>>>(r12, stats, ln1w, ln1b, nullptr, x1bf, 4194304);

  // FFN in nc chunks of cw: h = gelu(x1 @ fc_ch^T + fcb_ch); r2 (+)= h @ pj_ch^T
  for (int c = 0; c < nc; ++c) {
    cvt_f32_bf16<<<(int)(cn4 / 256), 256, 0, stream>>>(fcw + (size_t)c * cw * 2048, fc_ch, cn4);
    cvt_cols<<<(int)(cn4 / 256), 256, 0, stream>>>(pjw, pj_ch, c * cw, cwlog4, cn4);
    gemm256<<<dim3(cw / 256, 32, 1), 512, 0, stream>>>(x1bf, 2048, fc_ch, 2048, 2048,
                                                       fcb + c * cw, nullptr, nullptr, 0,
                                                       nullptr, hch, nullptr, cw, 1, nullptr);
    const int last = (c == nc - 1);
    gemm256<<<dim3(8, 32, 1), 512, 0, stream>>>(hch, cw, pj_ch, cw, cw,
                                                last ? pjb : nullptr, nullptr,
                                                last ? x1bf : nullptr, c > 0, r12, nullptr,
                                                nullptr, 2048, 0,
                                                last ? (stats + 2) : nullptr);
  }
  ln_apply<<<16384, 256, 0, stream>>>(r12, stats + 2, ln2w, ln2b, out, nullptr, 4194304);
}